// Round 3
// baseline (207.801 us; speedup 1.0000x reference)
//
#include <hip/hip_runtime.h>

// MSDeformAttn: B=4, Lq=Lv=5440 (M=21760), C=256, heads=8, levels=4, points=4, hd=32
// Level shapes: (64,64),(32,32),(16,16),(8,8) -> starts 0,4096,5120,5376
//
// R12: gemm12_cvt M-split 64x128 tiles for 2x occupancy.
//  - R9/R10/R11 all land 42-52us despite 3 different schedules -> shared
//    bottleneck is grid-limited TLP (850 blocks = 3.3/CU, Occupancy 19%,
//    all pipes idle: Mfma 5.7% VALU 8.1% HBM 26%).
//  - R12: 64-row tiles -> grid 1700 = 6.6 blocks/CU. LDS 24KB (6 blocks/CU),
//    acc[2][4] (~70 VGPR), __launch_bounds__(256,6). R11's verified frag-major
//    conflict-free dbuf + 1-barrier/kt + 1-tile-ahead loads kept unchanged.
//  - Predict: gemm12 -> 22-27us, Occupancy ~40%, MfmaUtil ~10%, conflicts 0.
//  - sample_f16 and gemm_single byte-identical to R9/R11.

typedef __attribute__((ext_vector_type(8))) _Float16 half8;
typedef __attribute__((ext_vector_type(4))) float f32x4;

typedef __attribute__((address_space(3))) unsigned int lds_uint;
typedef const __attribute__((address_space(1))) unsigned int g_uint;

__device__ __forceinline__ void load_lds16(const _Float16* g, _Float16* l) {
    __builtin_amdgcn_global_load_lds((g_uint*)g, (lds_uint*)l, 16, 0, 0);
}

__device__ __forceinline__ half8 splat8(_Float16 v) {
    half8 r = {v, v, v, v, v, v, v, v};
    return r;
}

#define M_TOTAL 21760

// -------- fused GEMM1+GEMM2 from f32 sources, 64x128 tiles, BK=32 -------------
// Fragment-major dbuf LDS. One __syncthreads per K-tile; next tile's global
// loads in flight across it. Grid 1700 blocks (6.6/CU).
__global__ __launch_bounds__(256, 6) void gemm12_cvt(
    const float* __restrict__ value, const float* __restrict__ query,
    const float* __restrict__ W_val, const float* __restrict__ W_off,
    const float* __restrict__ W_attn,
    const float* __restrict__ b_val, const float* __restrict__ b_off,
    const float* __restrict__ b_attn,
    _Float16* __restrict__ valh, _Float16* __restrict__ offh)
{
    __shared__ _Float16 Af[2][4 * 64 * 8];    // 4KB per buf
    __shared__ _Float16 Bf[2][4 * 128 * 8];   // 8KB per buf

    const bool g1 = blockIdx.x < 680;
    const int id = g1 ? blockIdx.x : blockIdx.x - 680;
    const int mt = g1 ? (id >> 1) : (id / 3);
    const int nt = g1 ? (id & 1) : (id % 3);
    const int NN = g1 ? 256 : 384;
    const float* A = g1 ? value : query;
    _Float16* C = g1 ? valh : offh;
    const int bm = mt * 64;
    const int bn = nt * 128;

    const float* W;
    int sW, nb;
    if (g1)            { W = W_val;  sW = 256; nb = bn; }
    else if (nt < 2)   { W = W_off;  sW = 256; nb = bn; }
    else               { W = W_attn; sW = 128; nb = 0;  }

    const int tid = threadIdx.x;
    const int wave = tid >> 6, lane = tid & 63;
    const int wm = (wave & 1) * 32, wn = (wave >> 1) * 64;
    const int ml = lane & 15;
    const int gq = lane >> 4;          // fragment k-octet 0..3

    // staging roles
    const int ar = tid & 63,  ag = tid >> 6;    // A: row ar, k-octet ag (0..3)
    const int bc = tid & 127, bh = tid >> 7;    // B: col bc, k-half bh (0/1)

    const float* aS = A + (size_t)(bm + ar) * 256 + ag * 8;
    const float* wS = W + (size_t)(bh * 16) * sW + nb + bc;

    float4 pa0, pa1;                   // 8 f32 of A (row ar, k ag*8..+7)
    float pb[16];                      // 16 f32 of B (col bc, k bh*16..+15)

    auto LOAD = [&](int kt) {
        const float* p = aS + kt * 32;
        pa0 = *(const float4*)(p + 0);
        pa1 = *(const float4*)(p + 4);
        const float* q = wS + (size_t)kt * 32 * sW;
#pragma unroll
        for (int e = 0; e < 16; ++e) pb[e] = q[(size_t)e * sW];
    };

    auto WRITE = [&](int buf) {
        const half8 ha = {(_Float16)pa0.x, (_Float16)pa0.y, (_Float16)pa0.z, (_Float16)pa0.w,
                          (_Float16)pa1.x, (_Float16)pa1.y, (_Float16)pa1.z, (_Float16)pa1.w};
        const half8 hb0 = {(_Float16)pb[0], (_Float16)pb[1], (_Float16)pb[2], (_Float16)pb[3],
                           (_Float16)pb[4], (_Float16)pb[5], (_Float16)pb[6], (_Float16)pb[7]};
        const half8 hb1 = {(_Float16)pb[8], (_Float16)pb[9], (_Float16)pb[10], (_Float16)pb[11],
                           (_Float16)pb[12], (_Float16)pb[13], (_Float16)pb[14], (_Float16)pb[15]};
        *(half8*)(&Af[buf][0] + ((ag * 64 + ar) << 3)) = ha;
        *(half8*)(&Bf[buf][0] + (((bh * 2) * 128 + bc) << 3)) = hb0;
        *(half8*)(&Bf[buf][0] + (((bh * 2 + 1) * 128 + bc) << 3)) = hb1;
    };

    const f32x4 zero4 = {0.f, 0.f, 0.f, 0.f};
    f32x4 acc[2][4];
#pragma unroll
    for (int i = 0; i < 2; ++i)
#pragma unroll
        for (int j = 0; j < 4; ++j) acc[i][j] = zero4;

    LOAD(0);
    int cur = 0;
    for (int kt = 0; kt < 8; ++kt) {
        WRITE(cur);                      // cvt + conflict-free ds_write_b128
        if (kt < 7) LOAD(kt + 1);        // next tile's loads in flight across barrier
        __syncthreads();                 // the only barrier per K-tile

        half8 af[2], bf[4];
        const _Float16* ab = &Af[cur][0] + ((size_t)gq * 64 << 3);
        const _Float16* bb = &Bf[cur][0] + ((size_t)gq * 128 << 3);
#pragma unroll
        for (int i = 0; i < 2; ++i)
            af[i] = *(const half8*)(ab + ((wm + i * 16 + ml) << 3));
#pragma unroll
        for (int j = 0; j < 4; ++j)
            bf[j] = *(const half8*)(bb + ((wn + j * 16 + ml) << 3));
#pragma unroll
        for (int i = 0; i < 2; ++i)
#pragma unroll
            for (int j = 0; j < 4; ++j)
                acc[i][j] = __builtin_amdgcn_mfma_f32_16x16x32_f16(af[i], bf[j], acc[i][j], 0, 0, 0);
        cur ^= 1;
    }

    const int r0 = (lane >> 4) * 4;
#pragma unroll
    for (int j = 0; j < 4; ++j) {
        const int col = bn + wn + j * 16 + ml;
        const float bj = g1 ? b_val[col] : (col < 256 ? b_off[col] : b_attn[col - 256]);
#pragma unroll
        for (int i = 0; i < 2; ++i) {
            const size_t rbase = (size_t)(bm + wm + i * 16 + r0) * NN + col;
#pragma unroll
            for (int r = 0; r < 4; ++r)
                C[rbase + (size_t)r * NN] = (_Float16)(acc[i][j][r] + bj);
        }
    }
}

// -------- R4 GEMM core (DMA staging, pitch 32) for the final GEMM -------------
__device__ __forceinline__ void gemm_core(
    const _Float16* __restrict__ A, const _Float16* __restrict__ Bt,
    const float* __restrict__ bias, float* __restrict__ Cv,
    int NN, int mt, int nt)
{
    __shared__ _Float16 Ah[128 * 32];
    __shared__ _Float16 Bh[64 * 32];

    const int tid = threadIdx.x;
    const int bm = mt * 128;
    const int bn = nt * 64;
    const int wave = tid >> 6, lane = tid & 63;
    const int wm = (wave & 1) * 64, wn = (wave >> 1) * 32;
    const int ml = lane & 15, kq = (lane >> 4) * 8;
    const int lr = lane >> 2;
    const int lk = (lane & 3) * 8;

    const f32x4 zero4 = {0.f, 0.f, 0.f, 0.f};
    f32x4 acc[4][2];
#pragma unroll
    for (int i = 0; i < 4; ++i)
#pragma unroll
        for (int j = 0; j < 2; ++j) acc[i][j] = zero4;

    for (int kt = 0; kt < 8; ++kt) {
        const int k0 = kt * 32;
        __syncthreads();
#pragma unroll
        for (int t = 0; t < 2; ++t) {
            const int row = wave * 32 + t * 16;
            load_lds16(A + (size_t)(bm + row + lr) * 256 + k0 + lk,
                       Ah + (size_t)row * 32);
        }
        {
            const int row = wave * 16;
            load_lds16(Bt + (size_t)(bn + row + lr) * 256 + k0 + lk,
                       Bh + (size_t)row * 32);
        }
        __syncthreads();

        half8 af[4], bf[2];
#pragma unroll
        for (int i = 0; i < 4; ++i)
            af[i] = *(const half8*)(Ah + (wm + i * 16 + ml) * 32 + kq);
#pragma unroll
        for (int j = 0; j < 2; ++j)
            bf[j] = *(const half8*)(Bh + (wn + j * 16 + ml) * 32 + kq);
#pragma unroll
        for (int i = 0; i < 4; ++i)
#pragma unroll
            for (int j = 0; j < 2; ++j)
                acc[i][j] = __builtin_amdgcn_mfma_f32_16x16x32_f16(af[i], bf[j], acc[i][j], 0, 0, 0);
    }

    const int r0 = (lane >> 4) * 4;
#pragma unroll
    for (int j = 0; j < 2; ++j) {
        const int col = bn + wn + j * 16 + ml;
        const float bj = bias[col];
#pragma unroll
        for (int i = 0; i < 4; ++i) {
            const size_t rbase = (size_t)(bm + wm + i * 16 + r0) * NN + col;
#pragma unroll
            for (int r = 0; r < 4; ++r)
                Cv[rbase + (size_t)r * NN] = acc[i][j][r] + bj;
        }
    }
}

__global__ __launch_bounds__(256) void gemm_single(
    const _Float16* __restrict__ A, const _Float16* __restrict__ Bt,
    const float* __restrict__ bias, float* __restrict__ Cv)
{
    const int id = blockIdx.x;
    gemm_core(A, Bt, bias, Cv, 256, id >> 2, id & 3);
}

// ---------------- sampler: batched gathers, schedule pinned -------------------
__global__ __launch_bounds__(256, 4) void sample_f16(
    const _Float16* __restrict__ valh,   // [M,256] f16
    const float* __restrict__ refp,      // [B,Lq,4,2]
    const _Float16* __restrict__ offh,   // [M,384] f16: 0-255 offsets, 256-383 logits
    const float* __restrict__ W_out,     // [256,256] f32 (k-major)
    _Float16* __restrict__ wto,          // [256,256] f16 (n-major, k-contig)
    _Float16* __restrict__ acc_out)      // [M,256] f16
{
    // fold W_out transpose into the first 256 blocks (consumed next dispatch)
    if (blockIdx.x < 256)
        wto[blockIdx.x * 256 + threadIdx.x] =
            (_Float16)W_out[threadIdx.x * 256 + blockIdx.x];

    const int wave = threadIdx.x >> 6, lane = threadIdx.x & 63;
    const int q2 = lane >> 5, sl = lane & 31;
    const int bq = blockIdx.x * 8 + wave * 2 + q2;    // 0..21759
    const int b = bq / 5440;
    const int h = sl >> 2;          // head
    const int d8 = (sl & 3) * 8;    // channel octet within head

    const _Float16* off_row = offh + (size_t)bq * 384 + h * 32;
    const _Float16* att_row = offh + (size_t)bq * 384 + 256 + h * 16;
    const float* rp = refp + (size_t)bq * 8;

    const half8 ofr0 = *(const half8*)(off_row);
    const half8 ofr1 = *(const half8*)(off_row + 8);
    const half8 ofr2 = *(const half8*)(off_row + 16);
    const half8 ofr3 = *(const half8*)(off_row + 24);
    float lg[16];
    {
        const half8 t0 = *(const half8*)(att_row);
        const half8 t1 = *(const half8*)(att_row + 8);
#pragma unroll
        for (int j = 0; j < 8; ++j) { lg[j] = (float)t0[j]; lg[8 + j] = (float)t1[j]; }
    }
    float mx = -1e30f;
#pragma unroll
    for (int i = 0; i < 16; ++i) mx = fmaxf(mx, lg[i]);
    float s = 0.f;
#pragma unroll
    for (int i = 0; i < 16; ++i) { lg[i] = __expf(lg[i] - mx); s += lg[i]; }
    const float inv = 1.f / s;

    const float4 rp01 = *(const float4*)rp;
    const float4 rp23 = *(const float4*)(rp + 4);
    const float rxs[4] = {rp01.x, rp01.z, rp23.x, rp23.z};
    const float rys[4] = {rp01.y, rp01.w, rp23.y, rp23.w};

    const int Ws_[4] = {64, 32, 16, 8};
    const int starts_[4] = {0, 4096, 5120, 5376};

    half8 acc = splat8((_Float16)0.f);
#pragma unroll
    for (int l = 0; l < 4; ++l) {
        const int W = Ws_[l];
        const float fW = (float)W;
        const _Float16* vbase = valh + ((size_t)(b * 5440 + starts_[l])) * 256 + h * 32 + d8;
        const float rx = rxs[l], ry = rys[l];

        int idx_[16];
        _Float16 w_[16];
#pragma unroll
        for (int p = 0; p < 4; ++p) {
            const int pi = l * 4 + p;
            const float aw = lg[pi] * inv;
            float ox, oy;
            {
                const half8 src = (pi < 8) ? ((pi < 4) ? ofr0 : ofr1)
                                           : ((pi < 12) ? ofr2 : ofr3);
                const int e = (pi & 3) * 2;
                ox = (float)src[e];
                oy = (float)src[e + 1];
            }
            const float x = fmaf(rx, fW, ox) - 0.5f;
            const float y = fmaf(ry, fW, oy) - 0.5f;
            const float x0f = floorf(x), y0f = floorf(y);
            const int x0 = (int)x0f, y0 = (int)y0f;
            const float wx = x - x0f, wy = y - y0f;
            const bool okx0 = ((unsigned)x0 < (unsigned)W);
            const bool okx1 = ((unsigned)(x0 + 1) < (unsigned)W);
            const bool oky0 = ((unsigned)y0 < (unsigned)W);
            const bool oky1 = ((unsigned)(y0 + 1) < (unsigned)W);
            const int xc0 = min(max(x0, 0), W - 1);
            const int xc1 = min(max(x0 + 1, 0), W - 1);
            const int yc0 = min(max(y0, 0), W - 1);
            const int yc1 = min(max(y0 + 1, 0), W - 1);
            w_[p * 4 + 0] = (_Float16)((okx0 & oky0) ? (1.f - wx) * (1.f - wy) * aw : 0.f);
            w_[p * 4 + 1] = (_Float16)((okx1 & oky0) ? wx * (1.f - wy) * aw : 0.f);
            w_[p * 4 + 2] = (_Float16)((okx0 & oky1) ? (1.f - wx) * wy * aw : 0.f);
            w_[p * 4 + 3] = (_Float16)((okx1 & oky1) ? wx * wy * aw : 0.f);
            idx_[p * 4 + 0] = (yc0 * W + xc0) * 256;
            idx_[p * 4 + 1] = (yc0 * W + xc1) * 256;
            idx_[p * 4 + 2] = (yc1 * W + xc0) * 256;
            idx_[p * 4 + 3] = (yc1 * W + xc1) * 256;
        }

        // pin: all 16 loads issue before any consumer (progressive vmcnt drain)
        __builtin_amdgcn_sched_barrier(0);
        half8 c_[16];
#pragma unroll
        for (int i = 0; i < 16; ++i)
            c_[i] = *(const half8*)(vbase + idx_[i]);
        __builtin_amdgcn_sched_barrier(0);
#pragma unroll
        for (int i = 0; i < 16; ++i)
            acc += c_[i] * splat8(w_[i]);
    }

    *(half8*)(acc_out + (size_t)bq * 256 + h * 32 + d8) = acc;
}

extern "C" void kernel_launch(void* const* d_in, const int* in_sizes, int n_in,
                              void* d_out, int out_size, void* d_ws, size_t ws_size,
                              hipStream_t stream) {
    const float* query  = (const float*)d_in[0];
    const float* refp   = (const float*)d_in[1];
    const float* value  = (const float*)d_in[2];
    const float* W_off  = (const float*)d_in[3];
    const float* b_off  = (const float*)d_in[4];
    const float* W_attn = (const float*)d_in[5];
    const float* b_attn = (const float*)d_in[6];
    const float* W_val  = (const float*)d_in[7];
    const float* b_val  = (const float*)d_in[8];
    const float* W_out  = (const float*)d_in[9];
    const float* b_out  = (const float*)d_in[10];
    float* out = (float*)d_out;

    const size_t M = M_TOTAL;

    _Float16* valh  = (_Float16*)d_ws;                // M*256
    _Float16* offh  = valh + M * 256;                 // M*384
    _Float16* acc16 = offh + M * 384;                 // M*256
    _Float16* wto   = acc16 + M * 256;                // 256*256

    dim3 blk(256);
    gemm12_cvt<<<dim3(1700), blk, 0, stream>>>(
        value, query, W_val, W_off, W_attn, b_val, b_off, b_attn, valh, offh);
    sample_f16<<<dim3(M / 8), blk, 0, stream>>>(valh, refp, offh, W_out, wto, acc16);
    gemm_single<<<dim3(680), blk, 0, stream>>>(acc16, wto, b_out, out);
}

// Round 4
// 176.295 us; speedup vs baseline: 1.1787x; 1.1787x over previous
//
#include <hip/hip_runtime.h>

// MSDeformAttn: B=4, Lq=Lv=5440 (M=21760), C=256, heads=8, levels=4, points=4, hd=32
// Level shapes: (64,64),(32,32),(16,16),(8,8) -> starts 0,4096,5120,5376
//
// R13: R12 with the register-spill bug fixed.
//  - R12 post-mortem: occupancy DID double (19->46%) but __launch_bounds__(256,6)
//    forced VGPR to 40 (< ~80 live: 24 staging f32 across barrier + 32 acc)
//    -> scratch spills: WRITE_SIZE 29->109MB, FETCH +14MB, dur 42->74us.
//    The 64x128 M-split grid (1700 blocks, 6.6/CU) is the right lever; the
//    min-waves constraint is the bug.
//  - R13: __launch_bounds__(256, 4) (VGPR cap 128; R11's identical pipeline
//    used 84). LDS 24KB -> 6 blocks/CU; ~84 VGPR -> 6 waves/SIMD naturally.
//  - Predict: VGPR ~84, WRITE ~29MB, FETCH ~58MB, gemm12 -> 22-28us,
//    Occupancy >=35%, MfmaUtil ~10%. Total ~150us.
//  - sample_f16 and gemm_single byte-identical to R9/R11/R12.

typedef __attribute__((ext_vector_type(8))) _Float16 half8;
typedef __attribute__((ext_vector_type(4))) float f32x4;

typedef __attribute__((address_space(3))) unsigned int lds_uint;
typedef const __attribute__((address_space(1))) unsigned int g_uint;

__device__ __forceinline__ void load_lds16(const _Float16* g, _Float16* l) {
    __builtin_amdgcn_global_load_lds((g_uint*)g, (lds_uint*)l, 16, 0, 0);
}

__device__ __forceinline__ half8 splat8(_Float16 v) {
    half8 r = {v, v, v, v, v, v, v, v};
    return r;
}

#define M_TOTAL 21760

// -------- fused GEMM1+GEMM2 from f32 sources, 64x128 tiles, BK=32 -------------
// Fragment-major dbuf LDS. One __syncthreads per K-tile; next tile's global
// loads in flight across it. Grid 1700 blocks (6.6/CU).
__global__ __launch_bounds__(256, 4) void gemm12_cvt(
    const float* __restrict__ value, const float* __restrict__ query,
    const float* __restrict__ W_val, const float* __restrict__ W_off,
    const float* __restrict__ W_attn,
    const float* __restrict__ b_val, const float* __restrict__ b_off,
    const float* __restrict__ b_attn,
    _Float16* __restrict__ valh, _Float16* __restrict__ offh)
{
    __shared__ _Float16 Af[2][4 * 64 * 8];    // 4KB per buf
    __shared__ _Float16 Bf[2][4 * 128 * 8];   // 8KB per buf

    const bool g1 = blockIdx.x < 680;
    const int id = g1 ? blockIdx.x : blockIdx.x - 680;
    const int mt = g1 ? (id >> 1) : (id / 3);
    const int nt = g1 ? (id & 1) : (id % 3);
    const int NN = g1 ? 256 : 384;
    const float* A = g1 ? value : query;
    _Float16* C = g1 ? valh : offh;
    const int bm = mt * 64;
    const int bn = nt * 128;

    const float* W;
    int sW, nb;
    if (g1)            { W = W_val;  sW = 256; nb = bn; }
    else if (nt < 2)   { W = W_off;  sW = 256; nb = bn; }
    else               { W = W_attn; sW = 128; nb = 0;  }

    const int tid = threadIdx.x;
    const int wave = tid >> 6, lane = tid & 63;
    const int wm = (wave & 1) * 32, wn = (wave >> 1) * 64;
    const int ml = lane & 15;
    const int gq = lane >> 4;          // fragment k-octet 0..3

    // staging roles
    const int ar = tid & 63,  ag = tid >> 6;    // A: row ar, k-octet ag (0..3)
    const int bc = tid & 127, bh = tid >> 7;    // B: col bc, k-half bh (0/1)

    const float* aS = A + (size_t)(bm + ar) * 256 + ag * 8;
    const float* wS = W + (size_t)(bh * 16) * sW + nb + bc;

    float4 pa0, pa1;                   // 8 f32 of A (row ar, k ag*8..+7)
    float pb[16];                      // 16 f32 of B (col bc, k bh*16..+15)

    auto LOAD = [&](int kt) {
        const float* p = aS + kt * 32;
        pa0 = *(const float4*)(p + 0);
        pa1 = *(const float4*)(p + 4);
        const float* q = wS + (size_t)kt * 32 * sW;
#pragma unroll
        for (int e = 0; e < 16; ++e) pb[e] = q[(size_t)e * sW];
    };

    auto WRITE = [&](int buf) {
        const half8 ha = {(_Float16)pa0.x, (_Float16)pa0.y, (_Float16)pa0.z, (_Float16)pa0.w,
                          (_Float16)pa1.x, (_Float16)pa1.y, (_Float16)pa1.z, (_Float16)pa1.w};
        const half8 hb0 = {(_Float16)pb[0], (_Float16)pb[1], (_Float16)pb[2], (_Float16)pb[3],
                           (_Float16)pb[4], (_Float16)pb[5], (_Float16)pb[6], (_Float16)pb[7]};
        const half8 hb1 = {(_Float16)pb[8], (_Float16)pb[9], (_Float16)pb[10], (_Float16)pb[11],
                           (_Float16)pb[12], (_Float16)pb[13], (_Float16)pb[14], (_Float16)pb[15]};
        *(half8*)(&Af[buf][0] + ((ag * 64 + ar) << 3)) = ha;
        *(half8*)(&Bf[buf][0] + (((bh * 2) * 128 + bc) << 3)) = hb0;
        *(half8*)(&Bf[buf][0] + (((bh * 2 + 1) * 128 + bc) << 3)) = hb1;
    };

    const f32x4 zero4 = {0.f, 0.f, 0.f, 0.f};
    f32x4 acc[2][4];
#pragma unroll
    for (int i = 0; i < 2; ++i)
#pragma unroll
        for (int j = 0; j < 4; ++j) acc[i][j] = zero4;

    LOAD(0);
    int cur = 0;
    for (int kt = 0; kt < 8; ++kt) {
        WRITE(cur);                      // cvt + conflict-free ds_write_b128
        if (kt < 7) LOAD(kt + 1);        // next tile's loads in flight across barrier
        __syncthreads();                 // the only barrier per K-tile

        half8 af[2], bf[4];
        const _Float16* ab = &Af[cur][0] + ((size_t)gq * 64 << 3);
        const _Float16* bb = &Bf[cur][0] + ((size_t)gq * 128 << 3);
#pragma unroll
        for (int i = 0; i < 2; ++i)
            af[i] = *(const half8*)(ab + ((wm + i * 16 + ml) << 3));
#pragma unroll
        for (int j = 0; j < 4; ++j)
            bf[j] = *(const half8*)(bb + ((wn + j * 16 + ml) << 3));
#pragma unroll
        for (int i = 0; i < 2; ++i)
#pragma unroll
            for (int j = 0; j < 4; ++j)
                acc[i][j] = __builtin_amdgcn_mfma_f32_16x16x32_f16(af[i], bf[j], acc[i][j], 0, 0, 0);
        cur ^= 1;
    }

    const int r0 = (lane >> 4) * 4;
#pragma unroll
    for (int j = 0; j < 4; ++j) {
        const int col = bn + wn + j * 16 + ml;
        const float bj = g1 ? b_val[col] : (col < 256 ? b_off[col] : b_attn[col - 256]);
#pragma unroll
        for (int i = 0; i < 2; ++i) {
            const size_t rbase = (size_t)(bm + wm + i * 16 + r0) * NN + col;
#pragma unroll
            for (int r = 0; r < 4; ++r)
                C[rbase + (size_t)r * NN] = (_Float16)(acc[i][j][r] + bj);
        }
    }
}

// -------- R4 GEMM core (DMA staging, pitch 32) for the final GEMM -------------
__device__ __forceinline__ void gemm_core(
    const _Float16* __restrict__ A, const _Float16* __restrict__ Bt,
    const float* __restrict__ bias, float* __restrict__ Cv,
    int NN, int mt, int nt)
{
    __shared__ _Float16 Ah[128 * 32];
    __shared__ _Float16 Bh[64 * 32];

    const int tid = threadIdx.x;
    const int bm = mt * 128;
    const int bn = nt * 64;
    const int wave = tid >> 6, lane = tid & 63;
    const int wm = (wave & 1) * 64, wn = (wave >> 1) * 32;
    const int ml = lane & 15, kq = (lane >> 4) * 8;
    const int lr = lane >> 2;
    const int lk = (lane & 3) * 8;

    const f32x4 zero4 = {0.f, 0.f, 0.f, 0.f};
    f32x4 acc[4][2];
#pragma unroll
    for (int i = 0; i < 4; ++i)
#pragma unroll
        for (int j = 0; j < 2; ++j) acc[i][j] = zero4;

    for (int kt = 0; kt < 8; ++kt) {
        const int k0 = kt * 32;
        __syncthreads();
#pragma unroll
        for (int t = 0; t < 2; ++t) {
            const int row = wave * 32 + t * 16;
            load_lds16(A + (size_t)(bm + row + lr) * 256 + k0 + lk,
                       Ah + (size_t)row * 32);
        }
        {
            const int row = wave * 16;
            load_lds16(Bt + (size_t)(bn + row + lr) * 256 + k0 + lk,
                       Bh + (size_t)row * 32);
        }
        __syncthreads();

        half8 af[4], bf[2];
#pragma unroll
        for (int i = 0; i < 4; ++i)
            af[i] = *(const half8*)(Ah + (wm + i * 16 + ml) * 32 + kq);
#pragma unroll
        for (int j = 0; j < 2; ++j)
            bf[j] = *(const half8*)(Bh + (wn + j * 16 + ml) * 32 + kq);
#pragma unroll
        for (int i = 0; i < 4; ++i)
#pragma unroll
            for (int j = 0; j < 2; ++j)
                acc[i][j] = __builtin_amdgcn_mfma_f32_16x16x32_f16(af[i], bf[j], acc[i][j], 0, 0, 0);
    }

    const int r0 = (lane >> 4) * 4;
#pragma unroll
    for (int j = 0; j < 2; ++j) {
        const int col = bn + wn + j * 16 + ml;
        const float bj = bias[col];
#pragma unroll
        for (int i = 0; i < 4; ++i) {
            const size_t rbase = (size_t)(bm + wm + i * 16 + r0) * NN + col;
#pragma unroll
            for (int r = 0; r < 4; ++r)
                Cv[rbase + (size_t)r * NN] = acc[i][j][r] + bj;
        }
    }
}

__global__ __launch_bounds__(256) void gemm_single(
    const _Float16* __restrict__ A, const _Float16* __restrict__ Bt,
    const float* __restrict__ bias, float* __restrict__ Cv)
{
    const int id = blockIdx.x;
    gemm_core(A, Bt, bias, Cv, 256, id >> 2, id & 3);
}

// ---------------- sampler: batched gathers, schedule pinned -------------------
__global__ __launch_bounds__(256, 4) void sample_f16(
    const _Float16* __restrict__ valh,   // [M,256] f16
    const float* __restrict__ refp,      // [B,Lq,4,2]
    const _Float16* __restrict__ offh,   // [M,384] f16: 0-255 offsets, 256-383 logits
    const float* __restrict__ W_out,     // [256,256] f32 (k-major)
    _Float16* __restrict__ wto,          // [256,256] f16 (n-major, k-contig)
    _Float16* __restrict__ acc_out)      // [M,256] f16
{
    // fold W_out transpose into the first 256 blocks (consumed next dispatch)
    if (blockIdx.x < 256)
        wto[blockIdx.x * 256 + threadIdx.x] =
            (_Float16)W_out[threadIdx.x * 256 + blockIdx.x];

    const int wave = threadIdx.x >> 6, lane = threadIdx.x & 63;
    const int q2 = lane >> 5, sl = lane & 31;
    const int bq = blockIdx.x * 8 + wave * 2 + q2;    // 0..21759
    const int b = bq / 5440;
    const int h = sl >> 2;          // head
    const int d8 = (sl & 3) * 8;    // channel octet within head

    const _Float16* off_row = offh + (size_t)bq * 384 + h * 32;
    const _Float16* att_row = offh + (size_t)bq * 384 + 256 + h * 16;
    const float* rp = refp + (size_t)bq * 8;

    const half8 ofr0 = *(const half8*)(off_row);
    const half8 ofr1 = *(const half8*)(off_row + 8);
    const half8 ofr2 = *(const half8*)(off_row + 16);
    const half8 ofr3 = *(const half8*)(off_row + 24);
    float lg[16];
    {
        const half8 t0 = *(const half8*)(att_row);
        const half8 t1 = *(const half8*)(att_row + 8);
#pragma unroll
        for (int j = 0; j < 8; ++j) { lg[j] = (float)t0[j]; lg[8 + j] = (float)t1[j]; }
    }
    float mx = -1e30f;
#pragma unroll
    for (int i = 0; i < 16; ++i) mx = fmaxf(mx, lg[i]);
    float s = 0.f;
#pragma unroll
    for (int i = 0; i < 16; ++i) { lg[i] = __expf(lg[i] - mx); s += lg[i]; }
    const float inv = 1.f / s;

    const float4 rp01 = *(const float4*)rp;
    const float4 rp23 = *(const float4*)(rp + 4);
    const float rxs[4] = {rp01.x, rp01.z, rp23.x, rp23.z};
    const float rys[4] = {rp01.y, rp01.w, rp23.y, rp23.w};

    const int Ws_[4] = {64, 32, 16, 8};
    const int starts_[4] = {0, 4096, 5120, 5376};

    half8 acc = splat8((_Float16)0.f);
#pragma unroll
    for (int l = 0; l < 4; ++l) {
        const int W = Ws_[l];
        const float fW = (float)W;
        const _Float16* vbase = valh + ((size_t)(b * 5440 + starts_[l])) * 256 + h * 32 + d8;
        const float rx = rxs[l], ry = rys[l];

        int idx_[16];
        _Float16 w_[16];
#pragma unroll
        for (int p = 0; p < 4; ++p) {
            const int pi = l * 4 + p;
            const float aw = lg[pi] * inv;
            float ox, oy;
            {
                const half8 src = (pi < 8) ? ((pi < 4) ? ofr0 : ofr1)
                                           : ((pi < 12) ? ofr2 : ofr3);
                const int e = (pi & 3) * 2;
                ox = (float)src[e];
                oy = (float)src[e + 1];
            }
            const float x = fmaf(rx, fW, ox) - 0.5f;
            const float y = fmaf(ry, fW, oy) - 0.5f;
            const float x0f = floorf(x), y0f = floorf(y);
            const int x0 = (int)x0f, y0 = (int)y0f;
            const float wx = x - x0f, wy = y - y0f;
            const bool okx0 = ((unsigned)x0 < (unsigned)W);
            const bool okx1 = ((unsigned)(x0 + 1) < (unsigned)W);
            const bool oky0 = ((unsigned)y0 < (unsigned)W);
            const bool oky1 = ((unsigned)(y0 + 1) < (unsigned)W);
            const int xc0 = min(max(x0, 0), W - 1);
            const int xc1 = min(max(x0 + 1, 0), W - 1);
            const int yc0 = min(max(y0, 0), W - 1);
            const int yc1 = min(max(y0 + 1, 0), W - 1);
            w_[p * 4 + 0] = (_Float16)((okx0 & oky0) ? (1.f - wx) * (1.f - wy) * aw : 0.f);
            w_[p * 4 + 1] = (_Float16)((okx1 & oky0) ? wx * (1.f - wy) * aw : 0.f);
            w_[p * 4 + 2] = (_Float16)((okx0 & oky1) ? (1.f - wx) * wy * aw : 0.f);
            w_[p * 4 + 3] = (_Float16)((okx1 & oky1) ? wx * wy * aw : 0.f);
            idx_[p * 4 + 0] = (yc0 * W + xc0) * 256;
            idx_[p * 4 + 1] = (yc0 * W + xc1) * 256;
            idx_[p * 4 + 2] = (yc1 * W + xc0) * 256;
            idx_[p * 4 + 3] = (yc1 * W + xc1) * 256;
        }

        // pin: all 16 loads issue before any consumer (progressive vmcnt drain)
        __builtin_amdgcn_sched_barrier(0);
        half8 c_[16];
#pragma unroll
        for (int i = 0; i < 16; ++i)
            c_[i] = *(const half8*)(vbase + idx_[i]);
        __builtin_amdgcn_sched_barrier(0);
#pragma unroll
        for (int i = 0; i < 16; ++i)
            acc += c_[i] * splat8(w_[i]);
    }

    *(half8*)(acc_out + (size_t)bq * 256 + h * 32 + d8) = acc;
}

extern "C" void kernel_launch(void* const* d_in, const int* in_sizes, int n_in,
                              void* d_out, int out_size, void* d_ws, size_t ws_size,
                              hipStream_t stream) {
    const float* query  = (const float*)d_in[0];
    const float* refp   = (const float*)d_in[1];
    const float* value  = (const float*)d_in[2];
    const float* W_off  = (const float*)d_in[3];
    const float* b_off  = (const float*)d_in[4];
    const float* W_attn = (const float*)d_in[5];
    const float* b_attn = (const float*)d_in[6];
    const float* W_val  = (const float*)d_in[7];
    const float* b_val  = (const float*)d_in[8];
    const float* W_out  = (const float*)d_in[9];
    const float* b_out  = (const float*)d_in[10];
    float* out = (float*)d_out;

    const size_t M = M_TOTAL;

    _Float16* valh  = (_Float16*)d_ws;                // M*256
    _Float16* offh  = valh + M * 256;                 // M*384
    _Float16* acc16 = offh + M * 384;                 // M*256
    _Float16* wto   = acc16 + M * 256;                // 256*256

    dim3 blk(256);
    gemm12_cvt<<<dim3(1700), blk, 0, stream>>>(
        value, query, W_val, W_off, W_attn, b_val, b_off, b_attn, valh, offh);
    sample_f16<<<dim3(M / 8), blk, 0, stream>>>(valh, refp, offh, W_out, wto, acc16);
    gemm_single<<<dim3(680), blk, 0, stream>>>(acc16, wto, b_out, out);
}

// Round 5
// 172.926 us; speedup vs baseline: 1.2017x; 1.0195x over previous
//
#include <hip/hip_runtime.h>

// MSDeformAttn: B=4, Lq=Lv=5440 (M=21760), C=256, heads=8, levels=4, points=4, hd=32
// Level shapes: (64,64),(32,32),(16,16),(8,8) -> starts 0,4096,5120,5376
//
// R14: dedup the sampler's scalar phase across the 4-lane (bq,h) group.
//  - R13 counters: sample_f16 is now the top kernel (51us, VALUBusy 51%,
//    MfmaUtil 0, HBM 13%, VGPR 64). The 4 lanes sharing (bq,h) (d8=0..3)
//    each recompute the SAME softmax (16 exp) + 16-point addr/weight calc
//    (~600 VALU) -> 4x redundant.
//  - R14: lane t = sl&3 computes LEVEL t's 4 points only (softmax via 4-lane
//    __shfl_xor butterfly, 4 exp/thread). Each corner packs to one u32:
//    row<<16 | f16(w). Exchange via 64 __shfl (ds_bpermute). All 64 gather
//    addresses known before the level loop.
//  - Predict: VALUBusy 51->~40%, sample 51 -> 38-42us, total ~162us.
//  - gemm12_cvt / gemm_single byte-identical to R13.

typedef __attribute__((ext_vector_type(8))) _Float16 half8;
typedef __attribute__((ext_vector_type(4))) _Float16 half4;
typedef __attribute__((ext_vector_type(4))) float f32x4;

typedef __attribute__((address_space(3))) unsigned int lds_uint;
typedef const __attribute__((address_space(1))) unsigned int g_uint;

__device__ __forceinline__ void load_lds16(const _Float16* g, _Float16* l) {
    __builtin_amdgcn_global_load_lds((g_uint*)g, (lds_uint*)l, 16, 0, 0);
}

__device__ __forceinline__ half8 splat8(_Float16 v) {
    half8 r = {v, v, v, v, v, v, v, v};
    return r;
}

#define M_TOTAL 21760

// -------- fused GEMM1+GEMM2 from f32 sources, 64x128 tiles, BK=32 -------------
// Fragment-major dbuf LDS. One __syncthreads per K-tile; next tile's global
// loads in flight across it. Grid 1700 blocks (6.6/CU).
__global__ __launch_bounds__(256, 4) void gemm12_cvt(
    const float* __restrict__ value, const float* __restrict__ query,
    const float* __restrict__ W_val, const float* __restrict__ W_off,
    const float* __restrict__ W_attn,
    const float* __restrict__ b_val, const float* __restrict__ b_off,
    const float* __restrict__ b_attn,
    _Float16* __restrict__ valh, _Float16* __restrict__ offh)
{
    __shared__ _Float16 Af[2][4 * 64 * 8];    // 4KB per buf
    __shared__ _Float16 Bf[2][4 * 128 * 8];   // 8KB per buf

    const bool g1 = blockIdx.x < 680;
    const int id = g1 ? blockIdx.x : blockIdx.x - 680;
    const int mt = g1 ? (id >> 1) : (id / 3);
    const int nt = g1 ? (id & 1) : (id % 3);
    const int NN = g1 ? 256 : 384;
    const float* A = g1 ? value : query;
    _Float16* C = g1 ? valh : offh;
    const int bm = mt * 64;
    const int bn = nt * 128;

    const float* W;
    int sW, nb;
    if (g1)            { W = W_val;  sW = 256; nb = bn; }
    else if (nt < 2)   { W = W_off;  sW = 256; nb = bn; }
    else               { W = W_attn; sW = 128; nb = 0;  }

    const int tid = threadIdx.x;
    const int wave = tid >> 6, lane = tid & 63;
    const int wm = (wave & 1) * 32, wn = (wave >> 1) * 64;
    const int ml = lane & 15;
    const int gq = lane >> 4;          // fragment k-octet 0..3

    // staging roles
    const int ar = tid & 63,  ag = tid >> 6;    // A: row ar, k-octet ag (0..3)
    const int bc = tid & 127, bh = tid >> 7;    // B: col bc, k-half bh (0/1)

    const float* aS = A + (size_t)(bm + ar) * 256 + ag * 8;
    const float* wS = W + (size_t)(bh * 16) * sW + nb + bc;

    float4 pa0, pa1;                   // 8 f32 of A (row ar, k ag*8..+7)
    float pb[16];                      // 16 f32 of B (col bc, k bh*16..+15)

    auto LOAD = [&](int kt) {
        const float* p = aS + kt * 32;
        pa0 = *(const float4*)(p + 0);
        pa1 = *(const float4*)(p + 4);
        const float* q = wS + (size_t)kt * 32 * sW;
#pragma unroll
        for (int e = 0; e < 16; ++e) pb[e] = q[(size_t)e * sW];
    };

    auto WRITE = [&](int buf) {
        const half8 ha = {(_Float16)pa0.x, (_Float16)pa0.y, (_Float16)pa0.z, (_Float16)pa0.w,
                          (_Float16)pa1.x, (_Float16)pa1.y, (_Float16)pa1.z, (_Float16)pa1.w};
        const half8 hb0 = {(_Float16)pb[0], (_Float16)pb[1], (_Float16)pb[2], (_Float16)pb[3],
                           (_Float16)pb[4], (_Float16)pb[5], (_Float16)pb[6], (_Float16)pb[7]};
        const half8 hb1 = {(_Float16)pb[8], (_Float16)pb[9], (_Float16)pb[10], (_Float16)pb[11],
                           (_Float16)pb[12], (_Float16)pb[13], (_Float16)pb[14], (_Float16)pb[15]};
        *(half8*)(&Af[buf][0] + ((ag * 64 + ar) << 3)) = ha;
        *(half8*)(&Bf[buf][0] + (((bh * 2) * 128 + bc) << 3)) = hb0;
        *(half8*)(&Bf[buf][0] + (((bh * 2 + 1) * 128 + bc) << 3)) = hb1;
    };

    const f32x4 zero4 = {0.f, 0.f, 0.f, 0.f};
    f32x4 acc[2][4];
#pragma unroll
    for (int i = 0; i < 2; ++i)
#pragma unroll
        for (int j = 0; j < 4; ++j) acc[i][j] = zero4;

    LOAD(0);
    int cur = 0;
    for (int kt = 0; kt < 8; ++kt) {
        WRITE(cur);                      // cvt + conflict-free ds_write_b128
        if (kt < 7) LOAD(kt + 1);        // next tile's loads in flight across barrier
        __syncthreads();                 // the only barrier per K-tile

        half8 af[2], bf[4];
        const _Float16* ab = &Af[cur][0] + ((size_t)gq * 64 << 3);
        const _Float16* bb = &Bf[cur][0] + ((size_t)gq * 128 << 3);
#pragma unroll
        for (int i = 0; i < 2; ++i)
            af[i] = *(const half8*)(ab + ((wm + i * 16 + ml) << 3));
#pragma unroll
        for (int j = 0; j < 4; ++j)
            bf[j] = *(const half8*)(bb + ((wn + j * 16 + ml) << 3));
#pragma unroll
        for (int i = 0; i < 2; ++i)
#pragma unroll
            for (int j = 0; j < 4; ++j)
                acc[i][j] = __builtin_amdgcn_mfma_f32_16x16x32_f16(af[i], bf[j], acc[i][j], 0, 0, 0);
        cur ^= 1;
    }

    const int r0 = (lane >> 4) * 4;
#pragma unroll
    for (int j = 0; j < 4; ++j) {
        const int col = bn + wn + j * 16 + ml;
        const float bj = g1 ? b_val[col] : (col < 256 ? b_off[col] : b_attn[col - 256]);
#pragma unroll
        for (int i = 0; i < 2; ++i) {
            const size_t rbase = (size_t)(bm + wm + i * 16 + r0) * NN + col;
#pragma unroll
            for (int r = 0; r < 4; ++r)
                C[rbase + (size_t)r * NN] = (_Float16)(acc[i][j][r] + bj);
        }
    }
}

// -------- R4 GEMM core (DMA staging, pitch 32) for the final GEMM -------------
__device__ __forceinline__ void gemm_core(
    const _Float16* __restrict__ A, const _Float16* __restrict__ Bt,
    const float* __restrict__ bias, float* __restrict__ Cv,
    int NN, int mt, int nt)
{
    __shared__ _Float16 Ah[128 * 32];
    __shared__ _Float16 Bh[64 * 32];

    const int tid = threadIdx.x;
    const int bm = mt * 128;
    const int bn = nt * 64;
    const int wave = tid >> 6, lane = tid & 63;
    const int wm = (wave & 1) * 64, wn = (wave >> 1) * 32;
    const int ml = lane & 15, kq = (lane >> 4) * 8;
    const int lr = lane >> 2;
    const int lk = (lane & 3) * 8;

    const f32x4 zero4 = {0.f, 0.f, 0.f, 0.f};
    f32x4 acc[4][2];
#pragma unroll
    for (int i = 0; i < 4; ++i)
#pragma unroll
        for (int j = 0; j < 2; ++j) acc[i][j] = zero4;

    for (int kt = 0; kt < 8; ++kt) {
        const int k0 = kt * 32;
        __syncthreads();
#pragma unroll
        for (int t = 0; t < 2; ++t) {
            const int row = wave * 32 + t * 16;
            load_lds16(A + (size_t)(bm + row + lr) * 256 + k0 + lk,
                       Ah + (size_t)row * 32);
        }
        {
            const int row = wave * 16;
            load_lds16(Bt + (size_t)(bn + row + lr) * 256 + k0 + lk,
                       Bh + (size_t)row * 32);
        }
        __syncthreads();

        half8 af[4], bf[2];
#pragma unroll
        for (int i = 0; i < 4; ++i)
            af[i] = *(const half8*)(Ah + (wm + i * 16 + ml) * 32 + kq);
#pragma unroll
        for (int j = 0; j < 2; ++j)
            bf[j] = *(const half8*)(Bh + (wn + j * 16 + ml) * 32 + kq);
#pragma unroll
        for (int i = 0; i < 4; ++i)
#pragma unroll
            for (int j = 0; j < 2; ++j)
                acc[i][j] = __builtin_amdgcn_mfma_f32_16x16x32_f16(af[i], bf[j], acc[i][j], 0, 0, 0);
    }

    const int r0 = (lane >> 4) * 4;
#pragma unroll
    for (int j = 0; j < 2; ++j) {
        const int col = bn + wn + j * 16 + ml;
        const float bj = bias[col];
#pragma unroll
        for (int i = 0; i < 4; ++i) {
            const size_t rbase = (size_t)(bm + wm + i * 16 + r0) * NN + col;
#pragma unroll
            for (int r = 0; r < 4; ++r)
                Cv[rbase + (size_t)r * NN] = acc[i][j][r] + bj;
        }
    }
}

__global__ __launch_bounds__(256) void gemm_single(
    const _Float16* __restrict__ A, const _Float16* __restrict__ Bt,
    const float* __restrict__ bias, float* __restrict__ Cv)
{
    const int id = blockIdx.x;
    gemm_core(A, Bt, bias, Cv, 256, id >> 2, id & 3);
}

// ---------------- sampler: group-dedup'd scalar phase + batched gathers -------
__global__ __launch_bounds__(256, 4) void sample_f16(
    const _Float16* __restrict__ valh,   // [M,256] f16
    const float* __restrict__ refp,      // [B,Lq,4,2]
    const _Float16* __restrict__ offh,   // [M,384] f16: 0-255 offsets, 256-383 logits
    const float* __restrict__ W_out,     // [256,256] f32 (k-major)
    _Float16* __restrict__ wto,          // [256,256] f16 (n-major, k-contig)
    _Float16* __restrict__ acc_out)      // [M,256] f16
{
    // fold W_out transpose into the first 256 blocks (consumed next dispatch)
    if (blockIdx.x < 256)
        wto[blockIdx.x * 256 + threadIdx.x] =
            (_Float16)W_out[threadIdx.x * 256 + blockIdx.x];

    const int wave = threadIdx.x >> 6, lane = threadIdx.x & 63;
    const int q2 = lane >> 5, sl = lane & 31;
    const int bq = blockIdx.x * 8 + wave * 2 + q2;    // 0..21759
    const int b = bq / 5440;
    const int h = sl >> 2;          // head
    const int t = sl & 3;           // dual role: my LEVEL (scalar phase) and d8 octet (gather)
    const int d8 = t * 8;

    // ---------- scalar phase: lane t computes level t's 4 points ----------
    const int Wt = 64 >> t;                       // {64,32,16,8}
    const float fW = (float)Wt;

    const half8 ofr = *(const half8*)(offh + (size_t)bq * 384 + h * 32 + t * 8);
    const half4 lgt = *(const half4*)(offh + (size_t)bq * 384 + 256 + h * 16 + t * 4);
    const float2 rxy = *(const float2*)(refp + (size_t)bq * 8 + t * 2);

    float lg[4];
#pragma unroll
    for (int p = 0; p < 4; ++p) lg[p] = (float)lgt[p];

    // group softmax: 4-lane butterfly (lanes t=0..3 share (bq,h))
    float mx = fmaxf(fmaxf(lg[0], lg[1]), fmaxf(lg[2], lg[3]));
    mx = fmaxf(mx, __shfl_xor(mx, 1));
    mx = fmaxf(mx, __shfl_xor(mx, 2));
    float s = 0.f;
#pragma unroll
    for (int p = 0; p < 4; ++p) { lg[p] = __expf(lg[p] - mx); s += lg[p]; }
    s += __shfl_xor(s, 1);
    s += __shfl_xor(s, 2);
    const float inv = 1.f / s;

    // per-corner pack: row(<=4095) << 16 | f16(weight)
    unsigned pk[16];
#pragma unroll
    for (int p = 0; p < 4; ++p) {
        const float aw = lg[p] * inv;
        const float ox = (float)ofr[p * 2];
        const float oy = (float)ofr[p * 2 + 1];
        const float x = fmaf(rxy.x, fW, ox) - 0.5f;
        const float y = fmaf(rxy.y, fW, oy) - 0.5f;
        const float x0f = floorf(x), y0f = floorf(y);
        const int x0 = (int)x0f, y0 = (int)y0f;
        const float wx = x - x0f, wy = y - y0f;
        const bool okx0 = ((unsigned)x0 < (unsigned)Wt);
        const bool okx1 = ((unsigned)(x0 + 1) < (unsigned)Wt);
        const bool oky0 = ((unsigned)y0 < (unsigned)Wt);
        const bool oky1 = ((unsigned)(y0 + 1) < (unsigned)Wt);
        const int xc0 = min(max(x0, 0), Wt - 1);
        const int xc1 = min(max(x0 + 1, 0), Wt - 1);
        const int yc0 = min(max(y0, 0), Wt - 1);
        const int yc1 = min(max(y0 + 1, 0), Wt - 1);
        const _Float16 w0 = (_Float16)((okx0 & oky0) ? (1.f - wx) * (1.f - wy) * aw : 0.f);
        const _Float16 w1 = (_Float16)((okx1 & oky0) ? wx * (1.f - wy) * aw : 0.f);
        const _Float16 w2 = (_Float16)((okx0 & oky1) ? (1.f - wx) * wy * aw : 0.f);
        const _Float16 w3 = (_Float16)((okx1 & oky1) ? wx * wy * aw : 0.f);
        pk[p * 4 + 0] = ((unsigned)(yc0 * Wt + xc0) << 16) |
                        (unsigned)__builtin_bit_cast(unsigned short, w0);
        pk[p * 4 + 1] = ((unsigned)(yc0 * Wt + xc1) << 16) |
                        (unsigned)__builtin_bit_cast(unsigned short, w1);
        pk[p * 4 + 2] = ((unsigned)(yc1 * Wt + xc0) << 16) |
                        (unsigned)__builtin_bit_cast(unsigned short, w2);
        pk[p * 4 + 3] = ((unsigned)(yc1 * Wt + xc1) << 16) |
                        (unsigned)__builtin_bit_cast(unsigned short, w3);
    }

    // ---------- gather phase: all lanes, per level, via group exchange ----
    const int starts_[4] = {0, 4096, 5120, 5376};
    const int gbase = lane & ~3;                  // group leader lane

    half8 acc = splat8((_Float16)0.f);
#pragma unroll
    for (int l = 0; l < 4; ++l) {
        const _Float16* vbase = valh + ((size_t)(b * 5440 + starts_[l])) * 256 + h * 32 + d8;
        const int src = gbase + l;

        unsigned q_[16];
#pragma unroll
        for (int c = 0; c < 16; ++c)
            q_[c] = (unsigned)__shfl((int)pk[c], src);

        // pin: all 16 loads issue before any consumer (progressive vmcnt drain)
        __builtin_amdgcn_sched_barrier(0);
        half8 c_[16];
#pragma unroll
        for (int c = 0; c < 16; ++c)
            c_[c] = *(const half8*)(vbase + ((size_t)(q_[c] >> 16) << 8));
        __builtin_amdgcn_sched_barrier(0);
#pragma unroll
        for (int c = 0; c < 16; ++c)
            acc += c_[c] * splat8(__builtin_bit_cast(_Float16, (unsigned short)(q_[c] & 0xffffu)));
    }

    *(half8*)(acc_out + (size_t)bq * 256 + h * 32 + d8) = acc;
}

extern "C" void kernel_launch(void* const* d_in, const int* in_sizes, int n_in,
                              void* d_out, int out_size, void* d_ws, size_t ws_size,
                              hipStream_t stream) {
    const float* query  = (const float*)d_in[0];
    const float* refp   = (const float*)d_in[1];
    const float* value  = (const float*)d_in[2];
    const float* W_off  = (const float*)d_in[3];
    const float* b_off  = (const float*)d_in[4];
    const float* W_attn = (const float*)d_in[5];
    const float* b_attn = (const float*)d_in[6];
    const float* W_val  = (const float*)d_in[7];
    const float* b_val  = (const float*)d_in[8];
    const float* W_out  = (const float*)d_in[9];
    const float* b_out  = (const float*)d_in[10];
    float* out = (float*)d_out;

    const size_t M = M_TOTAL;

    _Float16* valh  = (_Float16*)d_ws;                // M*256
    _Float16* offh  = valh + M * 256;                 // M*384
    _Float16* acc16 = offh + M * 384;                 // M*256
    _Float16* wto   = acc16 + M * 256;                // 256*256

    dim3 blk(256);
    gemm12_cvt<<<dim3(1700), blk, 0, stream>>>(
        value, query, W_val, W_off, W_attn, b_val, b_off, b_attn, valh, offh);
    sample_f16<<<dim3(M / 8), blk, 0, stream>>>(valh, refp, offh, W_out, wto, acc16);
    gemm_single<<<dim3(680), blk, 0, stream>>>(acc16, wto, b_out, out);
}